// Round 12
// baseline (356.144 us; speedup 1.0000x reference)
//
#include <hip/hip_runtime.h>

// BlockPatchMasking — exact reproduction, round 11 source (resubmitted after
// GPUAcquisitionTimeout; never benched).
// B=64,P=16384,F=3,MM=2 -> 128 rows. centers=10, knn=819, num_masks=9830.
// Bit-exact verified rounds 3-9 (absmax 0).
// d2 scheme (verified exact): q2 = ((x*x+y*y)+z*z) plain RN;
//   dot = fma chain; d2 = RN(RN(s2+q2) - RN(2*dot)).
//
// r10 ICE: V_CMP_NE_U32 $src_shared_base — LDS pointers through non-inlined
// template helpers defeat InferAddressSpaces -> flat null-check -> ISel bug.
// Fix: __forceinline__ all helpers, non-volatile sh, if constexpr dispatch.
// Structure (r10 theory): keys16 in packed registers (static indexing),
// candidates carry full 32-bit keys, LDS ~28KB, knn NT=512 @ 8 waves/EU.
// XCD swizzle kept (FETCH 53->12.4MB verified r9).

#define PP     16384
#define NROW   128
#define NC     10
#define KNN    819
#define NMASK  9830
#define HB     4096            // 12-bit pass0 bins
#define CAP    2048
#define UNI_WPR   512
#define WS_CL_U32 (NROW * 16)

__device__ __forceinline__ unsigned mapf(float f) {
    unsigned u = __float_as_uint(f);
    return (u & 0x80000000u) ? ~u : (u | 0x80000000u);
}

// Canonical d2 arithmetic. Explicit RN intrinsics are non-fusable and
// non-reassociable -> every inlined copy computes bit-identical results.
__device__ __forceinline__ float
d2_core(float cx, float cy, float cz, float sx, float sy, float sz, float s2)
{
    const float q2 = __fadd_rn(__fadd_rn(__fmul_rn(cx, cx), __fmul_rn(cy, cy)),
                               __fmul_rn(cz, cz));
    float dot = __fmul_rn(sx, cx);
    dot = __fmaf_rn(sy, cy, dot);
    dot = __fmaf_rn(sz, cz, dot);
    return __fsub_rn(__fadd_rn(s2, q2), __fmul_rn(2.0f, dot));
}

// ---- pick: find bin whose cumulative count crosses kk ----
// hist_pick: nbins <= blockDim, nbins multiple of 64, one bin per thread.
__device__ __forceinline__ void hist_pick(unsigned* hist, unsigned* sh, int nbins,
                                          int* kk_io, unsigned* bin_out)
{
    const int t = threadIdx.x, lane = t & 63, wv = t >> 6;
    const int kk = *kk_io;
    int c = 0, x = 0;
    if (t < nbins) {
        c = (int)hist[t]; x = c;
        #pragma unroll
        for (int off = 1; off < 64; off <<= 1) {
            const int y = __shfl_up(x, off, 64);
            if (lane >= off) x += y;
        }
        if (lane == 63) sh[4 + wv] = (unsigned)x;
    }
    __syncthreads();
    if (t < nbins) {
        int base = 0;
        for (int w = 0; w < wv; ++w) base += (int)sh[4 + w];
        x += base;
        const int e = x - c;
        if (e < kk && kk <= x) { sh[0] = (unsigned)t; sh[1] = (unsigned)(kk - e); }
    }
    __syncthreads();
    *bin_out = sh[0];
    *kk_io = (int)sh[1];
    __syncthreads();
}

// pick_bpt<BPT,NTT>: NTT*BPT bins, BPT contiguous bins/thread (static idx).
template <int BPT, int NTT>
__device__ __forceinline__ void pick_bpt(unsigned* hist, unsigned* sh,
                                         int* kk_io, unsigned* bin_out)
{
    const int t = threadIdx.x, lane = t & 63, wv = t >> 6;
    const int kk = *kk_io;
    unsigned c[BPT]; int s = 0;
    #pragma unroll
    for (int i = 0; i < BPT; ++i) { c[i] = hist[t * BPT + i]; s += (int)c[i]; }
    int x = s;
    #pragma unroll
    for (int off = 1; off < 64; off <<= 1) {
        const int y = __shfl_up(x, off, 64);
        if (lane >= off) x += y;
    }
    if (lane == 63) sh[4 + wv] = (unsigned)x;
    __syncthreads();
    int base = 0;
    for (int w = 0; w < wv; ++w) base += (int)sh[4 + w];
    x += base;
    const int e = x - s;
    if (e < kk && kk <= x) {
        int cum = e; unsigned bin = 0, rank = 0; bool found = false;
        #pragma unroll
        for (int i = 0; i < BPT; ++i) {
            if (!found && kk <= cum + (int)c[i]) {
                bin = (unsigned)(t * BPT + i); rank = (unsigned)(kk - cum); found = true;
            }
            cum += (int)c[i];
        }
        sh[0] = bin; sh[1] = rank;
    }
    __syncthreads();
    *bin_out = sh[0];
    *kk_io = (int)sh[1];
    __syncthreads();
}

// Narrow candidate list; cand_v holds FULL 32-bit keys (all sharing top-12
// prefix), cand_p the indices. Pure LDS — no recomputation.
template <int NTT>
__device__ __forceinline__ void
narrow_cand(unsigned* cand_v, unsigned short* cand_p,
            unsigned* ccnt, unsigned* hist, unsigned* sh,
            unsigned C, int kk, unsigned vpref,
            unsigned& vstar, unsigned& pstar)
{
    constexpr int CPT = CAP / NTT;
    const int t = threadIdx.x;
    #pragma unroll
    for (int li = 0; li < 2; ++li) {
        if (C <= 64u) break;
        const int shift = (li == 0) ? 10 : 0;
        for (int i = t; i < 1024; i += NTT) hist[i] = 0;
        __syncthreads();
        unsigned vv[CPT], pi_[CPT], bb[CPT]; bool va[CPT];
        #pragma unroll
        for (int i = 0; i < CPT; ++i) {
            const unsigned pos = (unsigned)(i * NTT + t);
            va[i] = pos < C;
            vv[i] = va[i] ? cand_v[pos] : 0u;
            pi_[i] = va[i] ? (unsigned)cand_p[pos] : 0u;
            bb[i] = (vv[i] >> shift) & 1023u;
            if (va[i]) atomicAdd(&hist[bb[i]], 1u);
        }
        __syncthreads();
        unsigned bl;
        if constexpr (NTT >= 1024) hist_pick(hist, sh, 1024, &kk, &bl);
        else                       pick_bpt<1024 / NTT, NTT>(hist, sh, &kk, &bl);
        vpref |= bl << shift;
        if (t == 0) *ccnt = 0;
        __syncthreads();
        #pragma unroll
        for (int i = 0; i < CPT; ++i)
            if (va[i] && bb[i] == bl) {
                const unsigned pos = atomicAdd(ccnt, 1u);
                cand_v[pos] = vv[i]; cand_p[pos] = (unsigned short)pi_[i];
            }
        __syncthreads();
        C = *ccnt;
        __syncthreads();
    }
    if (C <= 64u) {
        if (t < 64) {
            unsigned v = 0xFFFFFFFFu, pidx = 0xFFFFu;
            if ((unsigned)t < C) { v = cand_v[t]; pidx = (unsigned)cand_p[t]; }
            int rank = 0;
            for (unsigned j = 0; j < C; ++j) {
                const unsigned vj = __shfl(v, (int)j, 64);
                const unsigned pj = __shfl(pidx, (int)j, 64);
                if (vj < v || (vj == v && pj < pidx)) ++rank;
            }
            if ((unsigned)t < C && rank == kk - 1) { sh[0] = v; sh[1] = pidx; }
        }
        __syncthreads();
        vstar = sh[0]; pstar = sh[1];
        __syncthreads();
        return;
    }
    // >64 candidates share the full value vpref; select kk-th index.
    vstar = vpref;
    if (t < 128) hist[t] = 0;
    __syncthreads();
    {
        unsigned pi_[CPT], bb[CPT]; bool va[CPT];
        #pragma unroll
        for (int i = 0; i < CPT; ++i) {
            const unsigned pos = (unsigned)(i * NTT + t);
            va[i] = pos < C;
            pi_[i] = va[i] ? (unsigned)cand_p[pos] : 0u;
            bb[i] = pi_[i] >> 7;
            if (va[i]) atomicAdd(&hist[bb[i]], 1u);
        }
        __syncthreads();
        unsigned bl; hist_pick(hist, sh, 128, &kk, &bl);
        if (t == 0) *ccnt = 0;
        __syncthreads();
        #pragma unroll
        for (int i = 0; i < CPT; ++i)
            if (va[i] && bb[i] == bl)
                cand_p[atomicAdd(ccnt, 1u)] = (unsigned short)pi_[i];
        __syncthreads();
        C = *ccnt;                       // <= 128
        __syncthreads();
    }
    if (t < 64) {
        unsigned p0 = 0xFFFFFFFFu, p1 = 0xFFFFFFFFu;
        if ((unsigned)t < C)        p0 = (unsigned)cand_p[t];
        if ((unsigned)(t + 64) < C) p1 = (unsigned)cand_p[t + 64];
        int r0 = 0, r1 = 0;
        for (unsigned j = 0; j < C; ++j) {
            const unsigned pj = (j < 64) ? __shfl(p0, (int)j, 64)
                                         : __shfl(p1, (int)(j - 64), 64);
            if (pj < p0) ++r0;
            if (pj < p1) ++r1;
        }
        if ((unsigned)t < C && r0 == kk - 1)        sh[1] = p0;
        if ((unsigned)(t + 64) < C && r1 == kk - 1) sh[1] = p1;
    }
    __syncthreads();
    pstar = sh[1];
    __syncthreads();
}

// Exact, practically-unreachable fallback (crossing bin > CAP): full radix.
template <int NTT, class FK>
__device__ __forceinline__ void
fallback_radix(const FK& fullkey, unsigned* hist, unsigned* sh, int k,
               unsigned& vstar, unsigned& pstar)
{
    constexpr int PT = PP / NTT;
    const int t = threadIdx.x;
    int kk = k; unsigned prefix = 0;
    for (int pass = 0; pass < 4; ++pass) {
        const int shift = 24 - pass * 8;
        if (t < 256) hist[t] = 0;
        __syncthreads();
        for (int j = 0; j < PT; ++j) {
            const unsigned p = (unsigned)(j * NTT + t);
            const unsigned v = fullkey(p);
            bool in = (pass == 0) || ((v >> (shift + 8)) == prefix);
            if (in) atomicAdd(&hist[(v >> shift) & 255u], 1u);
        }
        __syncthreads();
        unsigned b; hist_pick(hist, sh, 256, &kk, &b);
        prefix = (prefix << 8) | b;
    }
    vstar = prefix;
    unsigned ipref = 0;
    for (int pass = 0; pass < 2; ++pass) {
        const int shift = 7 - pass * 7;
        if (t < 128) hist[t] = 0;
        __syncthreads();
        for (int j = 0; j < PT; ++j) {
            const unsigned p = (unsigned)(j * NTT + t);
            bool in = (fullkey(p) == vstar);
            if (in && pass != 0) in = ((p >> (shift + 7)) == ipref);
            if (in) atomicAdd(&hist[(p >> shift) & 127u], 1u);
        }
        __syncthreads();
        unsigned b; hist_pick(hist, sh, 128, &kk, &b);
        ipref = (ipref << 7) | b;
    }
    pstar = ipref;
}

// Register-key helpers: keys16 packed 2-per-u32, STATIC indexing only
// (all loops touching kr are fully unrolled).
#define KR_SET(kr, j, k16) do { \
    if ((j) & 1) kr[(j) >> 1] |= (k16) << 16; else kr[(j) >> 1] = (k16); } while (0)
#define KR_GET(kr, j) (((kr)[(j) >> 1] >> (((j) & 1) * 16)) & 0xFFFFu)

// =================== kernel A: centers (k=10), NT=1024 ===================
#define NTC 1024
#define PTC (PP / NTC)   // 16

extern "C" __global__ void __launch_bounds__(NTC, 4)
bpm_centers(const float* __restrict__ rand_centers, unsigned* __restrict__ ws_cl,
            unsigned* __restrict__ uni)
{
    __shared__ unsigned hist[HB];
    __shared__ unsigned cand_v[CAP];
    __shared__ unsigned short cand_p[CAP];
    __shared__ unsigned sh[24];
    __shared__ unsigned ccnt;
    __shared__ unsigned clist[16];
    __shared__ unsigned pcnt;

    const int bm = blockIdx.x;
    const int t  = threadIdx.x;
    if (t < UNI_WPR) uni[bm * UNI_WPR + t] = 0u;      // clear union bitmap

    const float* rcrow = rand_centers + (size_t)bm * PP;
    auto fullkey = [rcrow](unsigned p) -> unsigned { return mapf(rcrow[p]); };

    unsigned kr[PTC / 2];
    #pragma unroll
    for (int i = 0; i < HB / NTC; ++i) hist[t * (HB / NTC) + i] = 0;
    if (t == 0) { ccnt = 0; pcnt = 0; }
    __syncthreads();
    #pragma unroll
    for (int j = 0; j < PTC; ++j) {
        const unsigned p = (unsigned)(j * NTC + t);
        const unsigned k32 = fullkey(p);
        KR_SET(kr, j, k32 >> 16);
        atomicAdd(&hist[k32 >> 20], 1u);
    }
    __syncthreads();

    int kk = NC;
    unsigned b0; pick_bpt<HB / NTC, NTC>(hist, sh, &kk, &b0);
    #pragma unroll
    for (int j = 0; j < PTC; ++j) {
        const unsigned k16 = KR_GET(kr, j);
        if ((k16 >> 4) == b0) {
            const unsigned p = (unsigned)(j * NTC + t);
            const unsigned k32 = fullkey(p);
            const unsigned pos = atomicAdd(&ccnt, 1u);
            if (pos < CAP) { cand_v[pos] = k32; cand_p[pos] = (unsigned short)p; }
        }
    }
    __syncthreads();
    unsigned C = ccnt;
    __syncthreads();
    unsigned vs, ps;
    if (C <= CAP) narrow_cand<NTC>(cand_v, cand_p, &ccnt, hist, sh, C, kk, b0 << 20, vs, ps);
    else          fallback_radix<NTC>(fullkey, hist, sh, NC, vs, ps);
    const unsigned vs16 = vs >> 16;

    #pragma unroll
    for (int j = 0; j < PTC; ++j) {
        const unsigned p = (unsigned)(j * NTC + t);
        const unsigned k16 = KR_GET(kr, j);
        bool sel = k16 < vs16;
        if (k16 == vs16) {
            const unsigned v = fullkey(p);
            sel = (v < vs) || (v == vs && p <= ps);
        }
        if (sel) clist[atomicAdd(&pcnt, 1u)] = p;     // order irrelevant (union)
    }
    __syncthreads();
    if (t < NC) ws_cl[bm * 16 + t] = clist[t];
}

// ============ kernel B: knn (k=819) per (row,center), NT=512 ============
#define NTK 512
#define PTK (PP / NTK)   // 32

extern "C" __global__ void __launch_bounds__(NTK, 8)
bpm_knn(const float* __restrict__ centers, const unsigned* __restrict__ ws_cl,
        unsigned* __restrict__ uni)
{
    __shared__ unsigned hist[HB];
    __shared__ unsigned cand_v[CAP];
    __shared__ unsigned short cand_p[CAP];
    __shared__ unsigned sh[24];
    __shared__ unsigned ccnt;

    // XCD swizzle: all 10 blocks of a row share bid%8 -> same XCD L2 (r9:
    // FETCH 53->12.4MB). 16 rows/XCD x 196KB = 3.1MB < 4MB L2.
    const int bid   = blockIdx.x;
    const int inner = bid >> 3;                    // [0,160)
    const int bm    = (inner / NC) * 8 + (bid & 7);
    const int c     = inner % NC;
    const int b     = bm >> 1;
    const int t     = threadIdx.x;
    const float* crow = centers + (size_t)b * PP * 3;

    const int ci = (int)ws_cl[bm * 16 + c];
    const float sx = crow[ci * 3 + 0];
    const float sy = crow[ci * 3 + 1];
    const float sz = crow[ci * 3 + 2];
    const float s2 = __fadd_rn(__fadd_rn(__fmul_rn(sx, sx), __fmul_rn(sy, sy)),
                               __fmul_rn(sz, sz));
    auto fullkey = [crow, sx, sy, sz, s2](unsigned p) -> unsigned {
        const float cx = crow[3 * p + 0], cy = crow[3 * p + 1], cz = crow[3 * p + 2];
        return mapf(d2_core(cx, cy, cz, sx, sy, sz, s2));
    };

    unsigned kr[PTK / 2];
    #pragma unroll
    for (int i = 0; i < HB / NTK; ++i) hist[t * (HB / NTK) + i] = 0;
    if (t == 0) ccnt = 0;
    __syncthreads();
    #pragma unroll
    for (int j = 0; j < PTK; ++j) {
        const unsigned p = (unsigned)(j * NTK + t);
        const unsigned k32 = fullkey(p);
        KR_SET(kr, j, k32 >> 16);
        atomicAdd(&hist[k32 >> 20], 1u);
    }
    __syncthreads();

    int kk = KNN;
    unsigned b0; pick_bpt<HB / NTK, NTK>(hist, sh, &kk, &b0);
    #pragma unroll
    for (int j = 0; j < PTK; ++j) {
        const unsigned k16 = KR_GET(kr, j);
        if ((k16 >> 4) == b0) {
            const unsigned p = (unsigned)(j * NTK + t);
            const unsigned k32 = fullkey(p);
            const unsigned pos = atomicAdd(&ccnt, 1u);
            if (pos < CAP) { cand_v[pos] = k32; cand_p[pos] = (unsigned short)p; }
        }
    }
    __syncthreads();
    unsigned C = ccnt;
    __syncthreads();
    unsigned vs, ps;
    if (C <= CAP) narrow_cand<NTK>(cand_v, cand_p, &ccnt, hist, sh, C, kk, b0 << 20, vs, ps);
    else          fallback_radix<NTK>(fullkey, hist, sh, KNN, vs, ps);
    const unsigned vs16 = vs >> 16;

    unsigned* urow = uni + (size_t)bm * UNI_WPR;
    #pragma unroll
    for (int j = 0; j < PTK; ++j) {
        const unsigned p = (unsigned)(j * NTK + t);
        const unsigned k16 = KR_GET(kr, j);
        bool sel = k16 < vs16;
        if (k16 == vs16) {
            const unsigned v = fullkey(p);
            sel = (v < vs) || (v == vs && p <= ps);
        }
        const unsigned long long bmask = __ballot(sel);
        if ((t & 63) == 0 && bmask) {
            const int wbase = (int)(p >> 5);
            const unsigned lo = (unsigned)bmask;
            const unsigned hi = (unsigned)(bmask >> 32);
            if (lo) atomicOr(&urow[wbase], lo);
            if (hi) atomicOr(&urow[wbase + 1], hi);
        }
    }
}

// ============== kernel C: final (k=9830), NT=1024 ==============
extern "C" __global__ void __launch_bounds__(NTC, 4)
bpm_final(const float* __restrict__ rand_mask, const unsigned* __restrict__ uni,
          int* __restrict__ out)
{
    __shared__ unsigned hist[HB];
    __shared__ unsigned cand_v[CAP];
    __shared__ unsigned short cand_p[CAP];
    __shared__ unsigned sh[24];
    __shared__ unsigned ccnt;

    const int bm = blockIdx.x;
    const int t  = threadIdx.x;
    const float* rmrow = rand_mask + (size_t)bm * PP;
    const unsigned* urow = uni + (size_t)bm * UNI_WPR;

    auto fullkey = [rmrow, urow](unsigned p) -> unsigned {
        const float r = rmrow[p];
        const bool inb = (urow[p >> 5] >> (p & 31)) & 1u;
        return mapf(inb ? -r : r);
    };

    unsigned kr[PTC / 2];
    #pragma unroll
    for (int i = 0; i < HB / NTC; ++i) hist[t * (HB / NTC) + i] = 0;
    if (t == 0) ccnt = 0;
    __syncthreads();
    #pragma unroll
    for (int j = 0; j < PTC; ++j) {
        const unsigned p = (unsigned)(j * NTC + t);
        const unsigned k32 = fullkey(p);
        KR_SET(kr, j, k32 >> 16);
        atomicAdd(&hist[k32 >> 20], 1u);
    }
    __syncthreads();

    int kk = NMASK;
    unsigned b0; pick_bpt<HB / NTC, NTC>(hist, sh, &kk, &b0);
    #pragma unroll
    for (int j = 0; j < PTC; ++j) {
        const unsigned k16 = KR_GET(kr, j);
        if ((k16 >> 4) == b0) {
            const unsigned p = (unsigned)(j * NTC + t);
            const unsigned k32 = fullkey(p);
            const unsigned pos = atomicAdd(&ccnt, 1u);
            if (pos < CAP) { cand_v[pos] = k32; cand_p[pos] = (unsigned short)p; }
        }
    }
    __syncthreads();
    unsigned C = ccnt;
    __syncthreads();
    unsigned vs, ps;
    if (C <= CAP) narrow_cand<NTC>(cand_v, cand_p, &ccnt, hist, sh, C, kk, b0 << 20, vs, ps);
    else          fallback_radix<NTC>(fullkey, hist, sh, NMASK, vs, ps);
    const unsigned vs16 = vs >> 16;

    int* orow = out + (size_t)bm * PP;
    #pragma unroll
    for (int j = 0; j < PTC; ++j) {
        const unsigned p = (unsigned)(j * NTC + t);
        const unsigned k16 = KR_GET(kr, j);
        bool sel = k16 < vs16;
        if (k16 == vs16) {
            const unsigned v = fullkey(p);
            sel = (v < vs) || (v == vs && p <= ps);
        }
        orow[p] = sel ? 1 : 0;
    }
}

extern "C" void kernel_launch(void* const* d_in, const int* in_sizes, int n_in,
                              void* d_out, int out_size, void* d_ws, size_t ws_size,
                              hipStream_t stream)
{
    (void)in_sizes; (void)n_in; (void)out_size; (void)ws_size;
    const float* centers      = (const float*)d_in[0];
    const float* rand_centers = (const float*)d_in[1];
    const float* rand_mask    = (const float*)d_in[2];
    int* out = (int*)d_out;

    unsigned* ws_cl = (unsigned*)d_ws;          // ws_size >= 264KB verified r4-r9
    unsigned* uni   = ws_cl + WS_CL_U32;

    bpm_centers<<<dim3(NROW), dim3(NTC), 0, stream>>>(rand_centers, ws_cl, uni);
    bpm_knn<<<dim3(NROW * NC), dim3(NTK), 0, stream>>>(centers, ws_cl, uni);
    bpm_final<<<dim3(NROW), dim3(NTC), 0, stream>>>(rand_mask, uni, out);
}

// Round 13
// 253.939 us; speedup vs baseline: 1.4025x; 1.4025x over previous
//
#include <hip/hip_runtime.h>

// BlockPatchMasking — exact reproduction, round 13.
// B=64,P=16384,F=3,MM=2 -> 128 rows. centers=10, knn=819, num_masks=9830.
// Bit-exact verified rounds 3-9, 12 (absmax 0).
// d2 scheme (verified exact): q2 = ((x*x+y*y)+z*z) plain RN;
//   dot = fma chain; d2 = RN(RN(s2+q2) - RN(2*dot)).
//
// r12 post-mortem: knn 255us, WRITE_SIZE 440MB @ VGPR=32 — the (512,8)
// launch bound (64-VGPR cap) forced kr[16]+staging to scratch; 440MB/1.73TB/s
// = 254us (pure spill-BW-bound, arithmetic exact). Fix: (512,4) -> 128 cap;
// expected ~48-60 VGPR -> still 8 waves/SIMD at <=64, zero spill.
// Structure otherwise r12: register keys16 (static indexing), candidates
// carry full 32-bit keys, LDS ~28KB, XCD swizzle (FETCH 53->12.4MB, r9).

#define PP     16384
#define NROW   128
#define NC     10
#define KNN    819
#define NMASK  9830
#define HB     4096            // 12-bit pass0 bins
#define CAP    2048
#define UNI_WPR   512
#define WS_CL_U32 (NROW * 16)

__device__ __forceinline__ unsigned mapf(float f) {
    unsigned u = __float_as_uint(f);
    return (u & 0x80000000u) ? ~u : (u | 0x80000000u);
}

// Canonical d2 arithmetic. Explicit RN intrinsics are non-fusable and
// non-reassociable -> every inlined copy computes bit-identical results.
__device__ __forceinline__ float
d2_core(float cx, float cy, float cz, float sx, float sy, float sz, float s2)
{
    const float q2 = __fadd_rn(__fadd_rn(__fmul_rn(cx, cx), __fmul_rn(cy, cy)),
                               __fmul_rn(cz, cz));
    float dot = __fmul_rn(sx, cx);
    dot = __fmaf_rn(sy, cy, dot);
    dot = __fmaf_rn(sz, cz, dot);
    return __fsub_rn(__fadd_rn(s2, q2), __fmul_rn(2.0f, dot));
}

// ---- pick: find bin whose cumulative count crosses kk ----
// hist_pick: nbins <= blockDim, nbins multiple of 64, one bin per thread.
__device__ __forceinline__ void hist_pick(unsigned* hist, unsigned* sh, int nbins,
                                          int* kk_io, unsigned* bin_out)
{
    const int t = threadIdx.x, lane = t & 63, wv = t >> 6;
    const int kk = *kk_io;
    int c = 0, x = 0;
    if (t < nbins) {
        c = (int)hist[t]; x = c;
        #pragma unroll
        for (int off = 1; off < 64; off <<= 1) {
            const int y = __shfl_up(x, off, 64);
            if (lane >= off) x += y;
        }
        if (lane == 63) sh[4 + wv] = (unsigned)x;
    }
    __syncthreads();
    if (t < nbins) {
        int base = 0;
        for (int w = 0; w < wv; ++w) base += (int)sh[4 + w];
        x += base;
        const int e = x - c;
        if (e < kk && kk <= x) { sh[0] = (unsigned)t; sh[1] = (unsigned)(kk - e); }
    }
    __syncthreads();
    *bin_out = sh[0];
    *kk_io = (int)sh[1];
    __syncthreads();
}

// pick_bpt<BPT,NTT>: NTT*BPT bins, BPT contiguous bins/thread (static idx).
template <int BPT, int NTT>
__device__ __forceinline__ void pick_bpt(unsigned* hist, unsigned* sh,
                                         int* kk_io, unsigned* bin_out)
{
    const int t = threadIdx.x, lane = t & 63, wv = t >> 6;
    const int kk = *kk_io;
    unsigned c[BPT]; int s = 0;
    #pragma unroll
    for (int i = 0; i < BPT; ++i) { c[i] = hist[t * BPT + i]; s += (int)c[i]; }
    int x = s;
    #pragma unroll
    for (int off = 1; off < 64; off <<= 1) {
        const int y = __shfl_up(x, off, 64);
        if (lane >= off) x += y;
    }
    if (lane == 63) sh[4 + wv] = (unsigned)x;
    __syncthreads();
    int base = 0;
    for (int w = 0; w < wv; ++w) base += (int)sh[4 + w];
    x += base;
    const int e = x - s;
    if (e < kk && kk <= x) {
        int cum = e; unsigned bin = 0, rank = 0; bool found = false;
        #pragma unroll
        for (int i = 0; i < BPT; ++i) {
            if (!found && kk <= cum + (int)c[i]) {
                bin = (unsigned)(t * BPT + i); rank = (unsigned)(kk - cum); found = true;
            }
            cum += (int)c[i];
        }
        sh[0] = bin; sh[1] = rank;
    }
    __syncthreads();
    *bin_out = sh[0];
    *kk_io = (int)sh[1];
    __syncthreads();
}

// Narrow candidate list; cand_v holds FULL 32-bit keys (all sharing top-12
// prefix), cand_p the indices. Pure LDS — no recomputation.
template <int NTT>
__device__ __forceinline__ void
narrow_cand(unsigned* cand_v, unsigned short* cand_p,
            unsigned* ccnt, unsigned* hist, unsigned* sh,
            unsigned C, int kk, unsigned vpref,
            unsigned& vstar, unsigned& pstar)
{
    constexpr int CPT = CAP / NTT;
    const int t = threadIdx.x;
    #pragma unroll
    for (int li = 0; li < 2; ++li) {
        if (C <= 64u) break;
        const int shift = (li == 0) ? 10 : 0;
        for (int i = t; i < 1024; i += NTT) hist[i] = 0;
        __syncthreads();
        unsigned vv[CPT], pi_[CPT], bb[CPT]; bool va[CPT];
        #pragma unroll
        for (int i = 0; i < CPT; ++i) {
            const unsigned pos = (unsigned)(i * NTT + t);
            va[i] = pos < C;
            vv[i] = va[i] ? cand_v[pos] : 0u;
            pi_[i] = va[i] ? (unsigned)cand_p[pos] : 0u;
            bb[i] = (vv[i] >> shift) & 1023u;
            if (va[i]) atomicAdd(&hist[bb[i]], 1u);
        }
        __syncthreads();
        unsigned bl;
        if constexpr (NTT >= 1024) hist_pick(hist, sh, 1024, &kk, &bl);
        else                       pick_bpt<1024 / NTT, NTT>(hist, sh, &kk, &bl);
        vpref |= bl << shift;
        if (t == 0) *ccnt = 0;
        __syncthreads();
        #pragma unroll
        for (int i = 0; i < CPT; ++i)
            if (va[i] && bb[i] == bl) {
                const unsigned pos = atomicAdd(ccnt, 1u);
                cand_v[pos] = vv[i]; cand_p[pos] = (unsigned short)pi_[i];
            }
        __syncthreads();
        C = *ccnt;
        __syncthreads();
    }
    if (C <= 64u) {
        if (t < 64) {
            unsigned v = 0xFFFFFFFFu, pidx = 0xFFFFu;
            if ((unsigned)t < C) { v = cand_v[t]; pidx = (unsigned)cand_p[t]; }
            int rank = 0;
            for (unsigned j = 0; j < C; ++j) {
                const unsigned vj = __shfl(v, (int)j, 64);
                const unsigned pj = __shfl(pidx, (int)j, 64);
                if (vj < v || (vj == v && pj < pidx)) ++rank;
            }
            if ((unsigned)t < C && rank == kk - 1) { sh[0] = v; sh[1] = pidx; }
        }
        __syncthreads();
        vstar = sh[0]; pstar = sh[1];
        __syncthreads();
        return;
    }
    // >64 candidates share the full value vpref; select kk-th index.
    vstar = vpref;
    if (t < 128) hist[t] = 0;
    __syncthreads();
    {
        unsigned pi_[CPT], bb[CPT]; bool va[CPT];
        #pragma unroll
        for (int i = 0; i < CPT; ++i) {
            const unsigned pos = (unsigned)(i * NTT + t);
            va[i] = pos < C;
            pi_[i] = va[i] ? (unsigned)cand_p[pos] : 0u;
            bb[i] = pi_[i] >> 7;
            if (va[i]) atomicAdd(&hist[bb[i]], 1u);
        }
        __syncthreads();
        unsigned bl; hist_pick(hist, sh, 128, &kk, &bl);
        if (t == 0) *ccnt = 0;
        __syncthreads();
        #pragma unroll
        for (int i = 0; i < CPT; ++i)
            if (va[i] && bb[i] == bl)
                cand_p[atomicAdd(ccnt, 1u)] = (unsigned short)pi_[i];
        __syncthreads();
        C = *ccnt;                       // <= 128
        __syncthreads();
    }
    if (t < 64) {
        unsigned p0 = 0xFFFFFFFFu, p1 = 0xFFFFFFFFu;
        if ((unsigned)t < C)        p0 = (unsigned)cand_p[t];
        if ((unsigned)(t + 64) < C) p1 = (unsigned)cand_p[t + 64];
        int r0 = 0, r1 = 0;
        for (unsigned j = 0; j < C; ++j) {
            const unsigned pj = (j < 64) ? __shfl(p0, (int)j, 64)
                                         : __shfl(p1, (int)(j - 64), 64);
            if (pj < p0) ++r0;
            if (pj < p1) ++r1;
        }
        if ((unsigned)t < C && r0 == kk - 1)        sh[1] = p0;
        if ((unsigned)(t + 64) < C && r1 == kk - 1) sh[1] = p1;
    }
    __syncthreads();
    pstar = sh[1];
    __syncthreads();
}

// Exact, practically-unreachable fallback (crossing bin > CAP): full radix.
template <int NTT, class FK>
__device__ __forceinline__ void
fallback_radix(const FK& fullkey, unsigned* hist, unsigned* sh, int k,
               unsigned& vstar, unsigned& pstar)
{
    constexpr int PT = PP / NTT;
    const int t = threadIdx.x;
    int kk = k; unsigned prefix = 0;
    for (int pass = 0; pass < 4; ++pass) {
        const int shift = 24 - pass * 8;
        if (t < 256) hist[t] = 0;
        __syncthreads();
        for (int j = 0; j < PT; ++j) {
            const unsigned p = (unsigned)(j * NTT + t);
            const unsigned v = fullkey(p);
            bool in = (pass == 0) || ((v >> (shift + 8)) == prefix);
            if (in) atomicAdd(&hist[(v >> shift) & 255u], 1u);
        }
        __syncthreads();
        unsigned b; hist_pick(hist, sh, 256, &kk, &b);
        prefix = (prefix << 8) | b;
    }
    vstar = prefix;
    unsigned ipref = 0;
    for (int pass = 0; pass < 2; ++pass) {
        const int shift = 7 - pass * 7;
        if (t < 128) hist[t] = 0;
        __syncthreads();
        for (int j = 0; j < PT; ++j) {
            const unsigned p = (unsigned)(j * NTT + t);
            bool in = (fullkey(p) == vstar);
            if (in && pass != 0) in = ((p >> (shift + 7)) == ipref);
            if (in) atomicAdd(&hist[(p >> shift) & 127u], 1u);
        }
        __syncthreads();
        unsigned b; hist_pick(hist, sh, 128, &kk, &b);
        ipref = (ipref << 7) | b;
    }
    pstar = ipref;
}

// Register-key helpers: keys16 packed 2-per-u32, STATIC indexing only
// (all loops touching kr are fully unrolled).
#define KR_SET(kr, j, k16) do { \
    if ((j) & 1) kr[(j) >> 1] |= (k16) << 16; else kr[(j) >> 1] = (k16); } while (0)
#define KR_GET(kr, j) (((kr)[(j) >> 1] >> (((j) & 1) * 16)) & 0xFFFFu)

// =================== kernel A: centers (k=10), NT=1024 ===================
#define NTC 1024
#define PTC (PP / NTC)   // 16

extern "C" __global__ void __launch_bounds__(NTC, 2)
bpm_centers(const float* __restrict__ rand_centers, unsigned* __restrict__ ws_cl,
            unsigned* __restrict__ uni)
{
    __shared__ unsigned hist[HB];
    __shared__ unsigned cand_v[CAP];
    __shared__ unsigned short cand_p[CAP];
    __shared__ unsigned sh[24];
    __shared__ unsigned ccnt;
    __shared__ unsigned clist[16];
    __shared__ unsigned pcnt;

    const int bm = blockIdx.x;
    const int t  = threadIdx.x;
    if (t < UNI_WPR) uni[bm * UNI_WPR + t] = 0u;      // clear union bitmap

    const float* rcrow = rand_centers + (size_t)bm * PP;
    auto fullkey = [rcrow](unsigned p) -> unsigned { return mapf(rcrow[p]); };

    unsigned kr[PTC / 2];
    #pragma unroll
    for (int i = 0; i < HB / NTC; ++i) hist[t * (HB / NTC) + i] = 0;
    if (t == 0) { ccnt = 0; pcnt = 0; }
    __syncthreads();
    #pragma unroll
    for (int j = 0; j < PTC; ++j) {
        const unsigned p = (unsigned)(j * NTC + t);
        const unsigned k32 = fullkey(p);
        KR_SET(kr, j, k32 >> 16);
        atomicAdd(&hist[k32 >> 20], 1u);
    }
    __syncthreads();

    int kk = NC;
    unsigned b0; pick_bpt<HB / NTC, NTC>(hist, sh, &kk, &b0);
    #pragma unroll
    for (int j = 0; j < PTC; ++j) {
        const unsigned k16 = KR_GET(kr, j);
        if ((k16 >> 4) == b0) {
            const unsigned p = (unsigned)(j * NTC + t);
            const unsigned k32 = fullkey(p);
            const unsigned pos = atomicAdd(&ccnt, 1u);
            if (pos < CAP) { cand_v[pos] = k32; cand_p[pos] = (unsigned short)p; }
        }
    }
    __syncthreads();
    unsigned C = ccnt;
    __syncthreads();
    unsigned vs, ps;
    if (C <= CAP) narrow_cand<NTC>(cand_v, cand_p, &ccnt, hist, sh, C, kk, b0 << 20, vs, ps);
    else          fallback_radix<NTC>(fullkey, hist, sh, NC, vs, ps);
    const unsigned vs16 = vs >> 16;

    #pragma unroll
    for (int j = 0; j < PTC; ++j) {
        const unsigned p = (unsigned)(j * NTC + t);
        const unsigned k16 = KR_GET(kr, j);
        bool sel = k16 < vs16;
        if (k16 == vs16) {
            const unsigned v = fullkey(p);
            sel = (v < vs) || (v == vs && p <= ps);
        }
        if (sel) clist[atomicAdd(&pcnt, 1u)] = p;     // order irrelevant (union)
    }
    __syncthreads();
    if (t < NC) ws_cl[bm * 16 + t] = clist[t];
}

// ============ kernel B: knn (k=819) per (row,center), NT=512 ============
#define NTK 512
#define PTK (PP / NTK)   // 32

extern "C" __global__ void __launch_bounds__(NTK, 4)
bpm_knn(const float* __restrict__ centers, const unsigned* __restrict__ ws_cl,
        unsigned* __restrict__ uni)
{
    __shared__ unsigned hist[HB];
    __shared__ unsigned cand_v[CAP];
    __shared__ unsigned short cand_p[CAP];
    __shared__ unsigned sh[24];
    __shared__ unsigned ccnt;

    // XCD swizzle: all 10 blocks of a row share bid%8 -> same XCD L2 (r9:
    // FETCH 53->12.4MB). 16 rows/XCD x 196KB = 3.1MB < 4MB L2.
    const int bid   = blockIdx.x;
    const int inner = bid >> 3;                    // [0,160)
    const int bm    = (inner / NC) * 8 + (bid & 7);
    const int c     = inner % NC;
    const int b     = bm >> 1;
    const int t     = threadIdx.x;
    const float* crow = centers + (size_t)b * PP * 3;

    const int ci = (int)ws_cl[bm * 16 + c];
    const float sx = crow[ci * 3 + 0];
    const float sy = crow[ci * 3 + 1];
    const float sz = crow[ci * 3 + 2];
    const float s2 = __fadd_rn(__fadd_rn(__fmul_rn(sx, sx), __fmul_rn(sy, sy)),
                               __fmul_rn(sz, sz));
    auto fullkey = [crow, sx, sy, sz, s2](unsigned p) -> unsigned {
        const float cx = crow[3 * p + 0], cy = crow[3 * p + 1], cz = crow[3 * p + 2];
        return mapf(d2_core(cx, cy, cz, sx, sy, sz, s2));
    };

    unsigned kr[PTK / 2];
    #pragma unroll
    for (int i = 0; i < HB / NTK; ++i) hist[t * (HB / NTK) + i] = 0;
    if (t == 0) ccnt = 0;
    __syncthreads();
    #pragma unroll
    for (int j = 0; j < PTK; ++j) {
        const unsigned p = (unsigned)(j * NTK + t);
        const unsigned k32 = fullkey(p);
        KR_SET(kr, j, k32 >> 16);
        atomicAdd(&hist[k32 >> 20], 1u);
    }
    __syncthreads();

    int kk = KNN;
    unsigned b0; pick_bpt<HB / NTK, NTK>(hist, sh, &kk, &b0);
    #pragma unroll
    for (int j = 0; j < PTK; ++j) {
        const unsigned k16 = KR_GET(kr, j);
        if ((k16 >> 4) == b0) {
            const unsigned p = (unsigned)(j * NTK + t);
            const unsigned k32 = fullkey(p);
            const unsigned pos = atomicAdd(&ccnt, 1u);
            if (pos < CAP) { cand_v[pos] = k32; cand_p[pos] = (unsigned short)p; }
        }
    }
    __syncthreads();
    unsigned C = ccnt;
    __syncthreads();
    unsigned vs, ps;
    if (C <= CAP) narrow_cand<NTK>(cand_v, cand_p, &ccnt, hist, sh, C, kk, b0 << 20, vs, ps);
    else          fallback_radix<NTK>(fullkey, hist, sh, KNN, vs, ps);
    const unsigned vs16 = vs >> 16;

    unsigned* urow = uni + (size_t)bm * UNI_WPR;
    #pragma unroll
    for (int j = 0; j < PTK; ++j) {
        const unsigned p = (unsigned)(j * NTK + t);
        const unsigned k16 = KR_GET(kr, j);
        bool sel = k16 < vs16;
        if (k16 == vs16) {
            const unsigned v = fullkey(p);
            sel = (v < vs) || (v == vs && p <= ps);
        }
        const unsigned long long bmask = __ballot(sel);
        if ((t & 63) == 0 && bmask) {
            const int wbase = (int)(p >> 5);
            const unsigned lo = (unsigned)bmask;
            const unsigned hi = (unsigned)(bmask >> 32);
            if (lo) atomicOr(&urow[wbase], lo);
            if (hi) atomicOr(&urow[wbase + 1], hi);
        }
    }
}

// ============== kernel C: final (k=9830), NT=1024 ==============
extern "C" __global__ void __launch_bounds__(NTC, 2)
bpm_final(const float* __restrict__ rand_mask, const unsigned* __restrict__ uni,
          int* __restrict__ out)
{
    __shared__ unsigned hist[HB];
    __shared__ unsigned cand_v[CAP];
    __shared__ unsigned short cand_p[CAP];
    __shared__ unsigned sh[24];
    __shared__ unsigned ccnt;

    const int bm = blockIdx.x;
    const int t  = threadIdx.x;
    const float* rmrow = rand_mask + (size_t)bm * PP;
    const unsigned* urow = uni + (size_t)bm * UNI_WPR;

    auto fullkey = [rmrow, urow](unsigned p) -> unsigned {
        const float r = rmrow[p];
        const bool inb = (urow[p >> 5] >> (p & 31)) & 1u;
        return mapf(inb ? -r : r);
    };

    unsigned kr[PTC / 2];
    #pragma unroll
    for (int i = 0; i < HB / NTC; ++i) hist[t * (HB / NTC) + i] = 0;
    if (t == 0) ccnt = 0;
    __syncthreads();
    #pragma unroll
    for (int j = 0; j < PTC; ++j) {
        const unsigned p = (unsigned)(j * NTC + t);
        const unsigned k32 = fullkey(p);
        KR_SET(kr, j, k32 >> 16);
        atomicAdd(&hist[k32 >> 20], 1u);
    }
    __syncthreads();

    int kk = NMASK;
    unsigned b0; pick_bpt<HB / NTC, NTC>(hist, sh, &kk, &b0);
    #pragma unroll
    for (int j = 0; j < PTC; ++j) {
        const unsigned k16 = KR_GET(kr, j);
        if ((k16 >> 4) == b0) {
            const unsigned p = (unsigned)(j * NTC + t);
            const unsigned k32 = fullkey(p);
            const unsigned pos = atomicAdd(&ccnt, 1u);
            if (pos < CAP) { cand_v[pos] = k32; cand_p[pos] = (unsigned short)p; }
        }
    }
    __syncthreads();
    unsigned C = ccnt;
    __syncthreads();
    unsigned vs, ps;
    if (C <= CAP) narrow_cand<NTC>(cand_v, cand_p, &ccnt, hist, sh, C, kk, b0 << 20, vs, ps);
    else          fallback_radix<NTC>(fullkey, hist, sh, NMASK, vs, ps);
    const unsigned vs16 = vs >> 16;

    int* orow = out + (size_t)bm * PP;
    #pragma unroll
    for (int j = 0; j < PTC; ++j) {
        const unsigned p = (unsigned)(j * NTC + t);
        const unsigned k16 = KR_GET(kr, j);
        bool sel = k16 < vs16;
        if (k16 == vs16) {
            const unsigned v = fullkey(p);
            sel = (v < vs) || (v == vs && p <= ps);
        }
        orow[p] = sel ? 1 : 0;
    }
}

extern "C" void kernel_launch(void* const* d_in, const int* in_sizes, int n_in,
                              void* d_out, int out_size, void* d_ws, size_t ws_size,
                              hipStream_t stream)
{
    (void)in_sizes; (void)n_in; (void)out_size; (void)ws_size;
    const float* centers      = (const float*)d_in[0];
    const float* rand_centers = (const float*)d_in[1];
    const float* rand_mask    = (const float*)d_in[2];
    int* out = (int*)d_out;

    unsigned* ws_cl = (unsigned*)d_ws;          // ws_size >= 264KB verified r4-r12
    unsigned* uni   = ws_cl + WS_CL_U32;

    bpm_centers<<<dim3(NROW), dim3(NTC), 0, stream>>>(rand_centers, ws_cl, uni);
    bpm_knn<<<dim3(NROW * NC), dim3(NTK), 0, stream>>>(centers, ws_cl, uni);
    bpm_final<<<dim3(NROW), dim3(NTC), 0, stream>>>(rand_mask, uni, out);
}